// Round 1
// baseline (1862.074 us; speedup 1.0000x reference)
//
#include <hip/hip_runtime.h>

// Problem constants (from reference)
#define BATCH 2
#define HH 64
#define WW 1024
#define CC 64
#define NN 16384      // h*w = 32*512
#define KK 32
#define HW 65536      // H*W
// MLP: 67 -> 64 -> 64 -> 128

// Each thread owns one (b, n, k) row. Lanes 0..31 of each wave = k 0..31 of
// one point, lanes 32..63 = next point. Block = 128 threads = 4 points.
// feat row staged in LDS (stride 67 -> lane-to-bank map t*67 % 32 = t*3 % 32,
// bijective over 32 lanes -> only the free 2-way aliasing per wave64).
// Weights/bias/BN params are wave-uniform -> compiler emits s_load (to verify
// in disasm next round).

__global__ void pointnet_sa_f32(
    const float* __restrict__ xyz_proj,      // [B, H*W, 3]
    const float* __restrict__ points_proj,   // [B, H*W, C]
    const float* __restrict__ xyz_sampled,   // [B, N, 3]
    const int*   __restrict__ neighbor_idx,  // [B, N, K]
    const float* __restrict__ valid_mask,    // [B, N, K, 1]
    const float* __restrict__ W0, const float* __restrict__ b0,
    const float* __restrict__ g0, const float* __restrict__ be0,
    const float* __restrict__ W1, const float* __restrict__ b1,
    const float* __restrict__ g1, const float* __restrict__ be1,
    const float* __restrict__ W2, const float* __restrict__ b2,
    const float* __restrict__ g2, const float* __restrict__ be2,
    float* __restrict__ out)                 // [2][B*N][128] (duplicated tuple)
{
    __shared__ float s_feat[128 * 67];

    const int t   = threadIdx.x;
    const int gid = blockIdx.x * 128 + t;
    const int p   = gid >> 5;          // global point id in [0, B*N)
    const int k   = gid & 31;          // neighbor id
    const int b   = p >> 14;           // N = 16384

    // ---- gather + build feat row [67] in LDS ----
    const int   idx = neighbor_idx[(size_t)p * KK + k];
    const float m   = valid_mask[(size_t)p * KK + k];

    const float* xyzr = xyz_proj    + ((size_t)b * HW + idx) * 3;
    const float* nxyz = xyz_sampled + (size_t)p * 3;
    float* row = &s_feat[t * 67];

    row[0] = xyzr[0] * m - nxyz[0];
    row[1] = xyzr[1] * m - nxyz[1];
    row[2] = xyzr[2] * m - nxyz[2];

    const float4* ptsr = (const float4*)(points_proj + ((size_t)b * HW + idx) * CC);
    #pragma unroll
    for (int q = 0; q < 16; ++q) {
        float4 v = ptsr[q];
        row[3 + 4*q + 0] = v.x * m;
        row[3 + 4*q + 1] = v.y * m;
        row[3 + 4*q + 2] = v.z * m;
        row[3 + 4*q + 3] = v.w * m;
    }

    // ---- layer 0: 67 -> 64 ----
    {
        float acc[64];
        #pragma unroll
        for (int j = 0; j < 64; ++j) acc[j] = 0.f;
        for (int c = 0; c < 67; ++c) {
            const float f = row[c];
            #pragma unroll
            for (int j = 0; j < 64; ++j)
                acc[j] = fmaf(f, W0[c * 64 + j], acc[j]);
        }
        #pragma unroll
        for (int j = 0; j < 64; ++j) {
            float y = (acc[j] + b0[j]) * g0[j] + be0[j];
            row[j] = y > 0.f ? y : 0.f;
        }
    }

    // ---- layer 1: 64 -> 64 ----
    {
        float acc[64];
        #pragma unroll
        for (int j = 0; j < 64; ++j) acc[j] = 0.f;
        for (int c = 0; c < 64; ++c) {
            const float f = row[c];
            #pragma unroll
            for (int j = 0; j < 64; ++j)
                acc[j] = fmaf(f, W1[c * 64 + j], acc[j]);
        }
        #pragma unroll
        for (int j = 0; j < 64; ++j) {
            float y = (acc[j] + b1[j]) * g1[j] + be1[j];
            row[j] = y > 0.f ? y : 0.f;
        }
    }

    // ---- layer 2: 64 -> 128 ----
    float o[128];
    #pragma unroll
    for (int j = 0; j < 128; ++j) o[j] = 0.f;
    for (int c = 0; c < 64; ++c) {
        const float f = row[c];
        #pragma unroll
        for (int j = 0; j < 128; ++j)
            o[j] = fmaf(f, W2[c * 128 + j], o[j]);
    }
    #pragma unroll
    for (int j = 0; j < 128; ++j) {
        float y = (o[j] + b2[j]) * g2[j] + be2[j];
        o[j] = y > 0.f ? y : 0.f;
    }

    // ---- max-pool over K=32 (butterfly within each 32-lane half) ----
    #pragma unroll
    for (int j = 0; j < 128; ++j) {
        float v = o[j];
        v = fmaxf(v, __shfl_xor(v, 16));
        v = fmaxf(v, __shfl_xor(v, 8));
        v = fmaxf(v, __shfl_xor(v, 4));
        v = fmaxf(v, __shfl_xor(v, 2));
        v = fmaxf(v, __shfl_xor(v, 1));
        o[j] = v;
    }

    // ---- store (both tuple outputs are the same flat data) ----
    if (k == 0) {
        float* o0 = out + (size_t)p * 128;
        float* o1 = o0 + (size_t)BATCH * NN * 128;
        #pragma unroll
        for (int q = 0; q < 32; ++q) {
            float4 v = make_float4(o[4*q+0], o[4*q+1], o[4*q+2], o[4*q+3]);
            ((float4*)o0)[q] = v;
            ((float4*)o1)[q] = v;
        }
    }
}

extern "C" void kernel_launch(void* const* d_in, const int* in_sizes, int n_in,
                              void* d_out, int out_size, void* d_ws, size_t ws_size,
                              hipStream_t stream) {
    const float* xyz_proj    = (const float*)d_in[0];
    const float* points_proj = (const float*)d_in[1];
    const float* xyz_sampled = (const float*)d_in[2];
    const int*   neighbor_idx= (const int*)  d_in[3];
    const float* valid_mask  = (const float*)d_in[4];
    const float* W0 = (const float*)d_in[5];
    const float* b0 = (const float*)d_in[6];
    const float* g0 = (const float*)d_in[7];
    const float* be0= (const float*)d_in[8];
    const float* W1 = (const float*)d_in[9];
    const float* b1 = (const float*)d_in[10];
    const float* g1 = (const float*)d_in[11];
    const float* be1= (const float*)d_in[12];
    const float* W2 = (const float*)d_in[13];
    const float* b2 = (const float*)d_in[14];
    const float* g2 = (const float*)d_in[15];
    const float* be2= (const float*)d_in[16];

    const int total_rows = BATCH * NN * KK;   // 1,048,576
    const int block = 128;
    const int grid  = total_rows / block;     // 8192

    pointnet_sa_f32<<<grid, block, 0, stream>>>(
        xyz_proj, points_proj, xyz_sampled, neighbor_idx, valid_mask,
        W0, b0, g0, be0, W1, b1, g1, be1, W2, b2, g2, be2,
        (float*)d_out);
}

// Round 2
// 1153.509 us; speedup vs baseline: 1.6143x; 1.6143x over previous
//
#include <hip/hip_runtime.h>

// Problem constants (from reference)
#define NN 16384      // h*w = 32*512 sampled points per batch
#define KK 32
#define HW 65536      // H*W
#define OUT_HALF (2 * NN * 128)   // one tuple element, flat floats
// MLP: 67 -> 64 -> 64 -> 128, BN(inference) + ReLU, maxpool over K

// Thread = one (point, neighbor) row. 32 lanes = 32 neighbors of one point;
// wave64 = 2 points. Block 128 = 2 waves = 4 points.
// Activation row lives in LDS (stride 67: 67%32=3, gcd(3,32)=1 -> bijective
// lane->bank map, only the free 2-way wave64 aliasing).
// Accumulators chunked to 32 channels -> statically indexed -> stay in VGPRs
// (round 1 spilled acc[64]/o[128] to scratch: 797 MB WRITE_SIZE, VGPR=64).
// Weights indexed wave-uniformly -> scalar s_load path.

__global__ __launch_bounds__(128, 2)
void pointnet_sa_f32(
    const float* __restrict__ xyz_proj,      // [B, H*W, 3]
    const float* __restrict__ points_proj,   // [B, H*W, 64]
    const float* __restrict__ xyz_sampled,   // [B, N, 3]
    const int*   __restrict__ neighbor_idx,  // [B, N, K]
    const float* __restrict__ valid_mask,    // [B, N, K, 1]
    const float* __restrict__ W0, const float* __restrict__ b0,
    const float* __restrict__ g0, const float* __restrict__ be0,
    const float* __restrict__ W1, const float* __restrict__ b1,
    const float* __restrict__ g1, const float* __restrict__ be1,
    const float* __restrict__ W2, const float* __restrict__ b2,
    const float* __restrict__ g2, const float* __restrict__ be2,
    float* __restrict__ out)                 // [2][B*N][128] duplicated tuple
{
    __shared__ float s_feat[128 * 67];

    const int t   = threadIdx.x;
    const int gid = blockIdx.x * 128 + t;
    const int p   = gid >> 5;          // global point id in [0, B*N)
    const int kk  = gid & 31;          // neighbor id
    const int b   = p >> 14;           // N = 16384

    float* row = &s_feat[t * 67];

    // ---- gather + build feat row [67] in LDS ----
    const int   idx = neighbor_idx[(size_t)p * KK + kk];
    const float m   = valid_mask[(size_t)p * KK + kk];

    const float* xyzr = xyz_proj    + ((size_t)b * HW + idx) * 3;
    const float* nxyz = xyz_sampled + (size_t)p * 3;
    row[0] = xyzr[0] * m - nxyz[0];
    row[1] = xyzr[1] * m - nxyz[1];
    row[2] = xyzr[2] * m - nxyz[2];

    const float4* ptsr = (const float4*)(points_proj + ((size_t)b * HW + idx) * 64);
    #pragma unroll
    for (int q = 0; q < 16; ++q) {
        float4 v = ptsr[q];
        row[3 + 4*q + 0] = v.x * m;
        row[3 + 4*q + 1] = v.y * m;
        row[3 + 4*q + 2] = v.z * m;
        row[3 + 4*q + 3] = v.w * m;
    }
    // rows are thread-private: no barrier needed.

    float keep[32];
    float acc[32];

    // ---- layer 0: 67 -> 64 (two chunks of 32) ----
    {
        #pragma unroll
        for (int j = 0; j < 32; ++j) acc[j] = 0.f;
        for (int c = 0; c < 67; ++c) {
            const float f = row[c];
            #pragma unroll
            for (int j = 0; j < 32; ++j)
                acc[j] = fmaf(f, W0[c * 64 + j], acc[j]);
        }
        #pragma unroll
        for (int j = 0; j < 32; ++j) {
            float y = (acc[j] + b0[j]) * g0[j] + be0[j];
            keep[j] = y > 0.f ? y : 0.f;
        }
        #pragma unroll
        for (int j = 0; j < 32; ++j) acc[j] = 0.f;
        for (int c = 0; c < 67; ++c) {
            const float f = row[c];
            #pragma unroll
            for (int j = 0; j < 32; ++j)
                acc[j] = fmaf(f, W0[c * 64 + 32 + j], acc[j]);
        }
        #pragma unroll
        for (int j = 0; j < 32; ++j) {
            float y = (acc[j] + b0[32 + j]) * g0[32 + j] + be0[32 + j];
            row[32 + j] = y > 0.f ? y : 0.f;   // all reads of old row done
            row[j]      = keep[j];
        }
    }

    // ---- layer 1: 64 -> 64 (two chunks of 32) ----
    {
        #pragma unroll
        for (int j = 0; j < 32; ++j) acc[j] = 0.f;
        for (int c = 0; c < 64; ++c) {
            const float f = row[c];
            #pragma unroll
            for (int j = 0; j < 32; ++j)
                acc[j] = fmaf(f, W1[c * 64 + j], acc[j]);
        }
        #pragma unroll
        for (int j = 0; j < 32; ++j) {
            float y = (acc[j] + b1[j]) * g1[j] + be1[j];
            keep[j] = y > 0.f ? y : 0.f;
        }
        #pragma unroll
        for (int j = 0; j < 32; ++j) acc[j] = 0.f;
        for (int c = 0; c < 64; ++c) {
            const float f = row[c];
            #pragma unroll
            for (int j = 0; j < 32; ++j)
                acc[j] = fmaf(f, W1[c * 64 + 32 + j], acc[j]);
        }
        #pragma unroll
        for (int j = 0; j < 32; ++j) {
            float y = (acc[j] + b1[32 + j]) * g1[32 + j] + be1[32 + j];
            row[32 + j] = y > 0.f ? y : 0.f;
            row[j]      = keep[j];
        }
    }

    // ---- layer 2: 64 -> 128 (four chunks of 32), fused maxpool + store ----
    for (int oc = 0; oc < 4; ++oc) {
        #pragma unroll
        for (int j = 0; j < 32; ++j) acc[j] = 0.f;
        for (int c = 0; c < 64; ++c) {
            const float f = row[c];
            #pragma unroll
            for (int j = 0; j < 32; ++j)
                acc[j] = fmaf(f, W2[c * 128 + oc * 32 + j], acc[j]);
        }
        #pragma unroll
        for (int j = 0; j < 32; ++j) {
            float y = (acc[j] + b2[oc * 32 + j]) * g2[oc * 32 + j] + be2[oc * 32 + j];
            y = y > 0.f ? y : 0.f;
            // maxpool over the 32 neighbors (butterfly within 32-lane half)
            y = fmaxf(y, __shfl_xor(y, 16));
            y = fmaxf(y, __shfl_xor(y, 8));
            y = fmaxf(y, __shfl_xor(y, 4));
            y = fmaxf(y, __shfl_xor(y, 2));
            y = fmaxf(y, __shfl_xor(y, 1));
            acc[j] = y;
        }
        if (kk == 0) {
            float* o0 = out + (size_t)p * 128 + oc * 32;
            float* o1 = o0 + OUT_HALF;
            #pragma unroll
            for (int q = 0; q < 8; ++q) {
                float4 v = make_float4(acc[4*q+0], acc[4*q+1], acc[4*q+2], acc[4*q+3]);
                ((float4*)o0)[q] = v;
                ((float4*)o1)[q] = v;
            }
        }
    }
}

extern "C" void kernel_launch(void* const* d_in, const int* in_sizes, int n_in,
                              void* d_out, int out_size, void* d_ws, size_t ws_size,
                              hipStream_t stream) {
    const float* xyz_proj    = (const float*)d_in[0];
    const float* points_proj = (const float*)d_in[1];
    const float* xyz_sampled = (const float*)d_in[2];
    const int*   neighbor_idx= (const int*)  d_in[3];
    const float* valid_mask  = (const float*)d_in[4];
    const float* W0 = (const float*)d_in[5];
    const float* b0 = (const float*)d_in[6];
    const float* g0 = (const float*)d_in[7];
    const float* be0= (const float*)d_in[8];
    const float* W1 = (const float*)d_in[9];
    const float* b1 = (const float*)d_in[10];
    const float* g1 = (const float*)d_in[11];
    const float* be1= (const float*)d_in[12];
    const float* W2 = (const float*)d_in[13];
    const float* b2 = (const float*)d_in[14];
    const float* g2 = (const float*)d_in[15];
    const float* be2= (const float*)d_in[16];

    const int total_rows = 2 * NN * KK;   // 1,048,576
    const int block = 128;
    const int grid  = total_rows / block; // 8192

    pointnet_sa_f32<<<grid, block, 0, stream>>>(
        xyz_proj, points_proj, xyz_sampled, neighbor_idx, valid_mask,
        W0, b0, g0, be0, W1, b1, g1, be1, W2, b2, g2, be2,
        (float*)d_out);
}

// Round 3
// 157.108 us; speedup vs baseline: 11.8522x; 7.3421x over previous
//
#include <hip/hip_runtime.h>
#include <stdint.h>

// Problem constants
#define NN 16384                  // sampled points per batch (h*w)
#define HW 65536                  // H*W
#define OUT_HALF (2 * NN * 128)   // one tuple element, flat floats
// MLP: 67 -> 64 -> 64 -> 128 (BN folded), maxpool over K=32 neighbors.
//
// Strategy: one wave = one point; the 32 neighbors are the M=32 rows of a
// sequence of 16x16x32 bf16 MFMAs. fp32 accuracy recovered via hi/lo bf16
// split of BOTH operands, 3 MFMA passes: ah*wh + al*wh + ah*wl (rel ~2^-15).
// Weights pre-swizzled into MFMA B-fragment order (hi/lo) by a prep kernel,
// with BN scale g folded into W and bias' = b*g + be.
//
// Fragment maps (gfx950 16x16x32 bf16):
//   A[16x32]: row = lane&15, k = 8*(lane>>4) + e   (e = 0..7)
//   B[32x16]: col = lane&15, k = 8*(lane>>4) + e
//   C/D:      col = lane&15, row = 4*(lane>>4) + reg   [m89 verified]
// Layer-0 K order: k 0..63 = points channels (feat rows 3..66 of W0),
//                  k 64..66 = xyz_diff (W0 rows 0..2), k 67..95 = zero pad.

typedef __attribute__((ext_vector_type(8))) short bf16x8;
typedef __attribute__((ext_vector_type(4))) float f32x4;

// ws layout, uint16 units:
//  L0 hi @ 0      [3 kt][4 nt][64 lane][8 e]  (6144)
//  L0 lo @ 6144
//  L1 hi @ 12288  [2][4][64][8]               (4096)
//  L1 lo @ 16384
//  L2 hi @ 20480  [2][8][64][8]               (8192)
//  L2 lo @ 28672
//  bias  @ 36864  f32[256]: bias0[64], bias1[64], bias2[128]
#define WS_L0H 0
#define WS_L0L 6144
#define WS_L1H 12288
#define WS_L1L 16384
#define WS_L2H 20480
#define WS_L2L 28672
#define WS_BIAS 36864

__device__ inline uint16_t f32_to_bf16_rne(float x) {
    uint32_t u = __float_as_uint(x);
    uint32_t r = (u + 0x7FFFu + ((u >> 16) & 1u)) >> 16;
    return (uint16_t)r;
}
__device__ inline float bf16_to_f32(uint16_t h) {
    return __uint_as_float(((uint32_t)h) << 16);
}
__device__ inline void split2(float v, uint16_t* hi, uint16_t* lo) {
    uint16_t h = f32_to_bf16_rne(v);
    *hi = h;
    *lo = f32_to_bf16_rne(v - bf16_to_f32(h));
}

// ---------------- weight prep ----------------
__global__ void prep_weights(
    const float* __restrict__ W0, const float* __restrict__ b0,
    const float* __restrict__ g0, const float* __restrict__ be0,
    const float* __restrict__ W1, const float* __restrict__ b1,
    const float* __restrict__ g1, const float* __restrict__ be1,
    const float* __restrict__ W2, const float* __restrict__ b2,
    const float* __restrict__ g2, const float* __restrict__ be2,
    uint16_t* __restrict__ ws)
{
    const int tid = blockIdx.x * blockDim.x + threadIdx.x;
    const int nth = gridDim.x * blockDim.x;

    // L0: [3][4][64][8], k: 0..63 -> W0 row 3+k; 64..66 -> W0 row k-64; else 0
    for (int i = tid; i < 6144; i += nth) {
        int e = i & 7, lane = (i >> 3) & 63, nt = (i >> 9) & 3, kt = i >> 11;
        int k = kt * 32 + 8 * (lane >> 4) + e;
        int n = nt * 16 + (lane & 15);
        float v = 0.f;
        if (k < 64)       v = W0[(3 + k) * 64 + n] * g0[n];
        else if (k < 67)  v = W0[(k - 64) * 64 + n] * g0[n];
        uint16_t hi, lo; split2(v, &hi, &lo);
        ws[WS_L0H + i] = hi; ws[WS_L0L + i] = lo;
    }
    // L1: [2][4][64][8]
    for (int i = tid; i < 4096; i += nth) {
        int e = i & 7, lane = (i >> 3) & 63, nt = (i >> 9) & 3, kt = i >> 11;
        int k = kt * 32 + 8 * (lane >> 4) + e;
        int n = nt * 16 + (lane & 15);
        float v = W1[k * 64 + n] * g1[n];
        uint16_t hi, lo; split2(v, &hi, &lo);
        ws[WS_L1H + i] = hi; ws[WS_L1L + i] = lo;
    }
    // L2: [2][8][64][8]
    for (int i = tid; i < 8192; i += nth) {
        int e = i & 7, lane = (i >> 3) & 63, nt = (i >> 9) & 7, kt = i >> 12;
        int k = kt * 32 + 8 * (lane >> 4) + e;
        int n = nt * 16 + (lane & 15);
        float v = W2[k * 128 + n] * g2[n];
        uint16_t hi, lo; split2(v, &hi, &lo);
        ws[WS_L2H + i] = hi; ws[WS_L2L + i] = lo;
    }
    // biases
    float* bias = (float*)(ws + WS_BIAS);
    for (int i = tid; i < 64; i += nth)  bias[i]       = b0[i] * g0[i] + be0[i];
    for (int i = tid; i < 64; i += nth)  bias[64 + i]  = b1[i] * g1[i] + be1[i];
    for (int i = tid; i < 128; i += nth) bias[128 + i] = b2[i] * g2[i] + be2[i];
}

// ---------------- main kernel ----------------
__device__ inline void split_frag8(const float* f, bf16x8* hi, bf16x8* lo) {
    #pragma unroll
    for (int e = 0; e < 8; ++e) {
        uint16_t h, l;
        split2(f[e], &h, &l);
        (*hi)[e] = (short)h;
        (*lo)[e] = (short)l;
    }
}

__device__ inline f32x4 mfma3(bf16x8 ah, bf16x8 al, bf16x8 wh, bf16x8 wl, f32x4 c) {
    c = __builtin_amdgcn_mfma_f32_16x16x32_bf16(ah, wh, c, 0, 0, 0);
    c = __builtin_amdgcn_mfma_f32_16x16x32_bf16(al, wh, c, 0, 0, 0);
    c = __builtin_amdgcn_mfma_f32_16x16x32_bf16(ah, wl, c, 0, 0, 0);
    return c;
}

__global__ __launch_bounds__(256)
void pointnet_mfma(
    const float* __restrict__ xyz_proj,      // [B, H*W, 3]
    const float* __restrict__ points_proj,   // [B, H*W, 64]
    const float* __restrict__ xyz_sampled,   // [B, N, 3]
    const int*   __restrict__ nidx,          // [B, N, 32]
    const float* __restrict__ vmask,         // [B, N, 32, 1]
    const uint16_t* __restrict__ wf,         // pre-swizzled weights
    float* __restrict__ out)
{
    __shared__ __align__(16) float s_feat[4][32][68];
    __shared__ __align__(16) float s_xyz[4][32][4];

    const int t    = threadIdx.x & 63;
    const int widx = threadIdx.x >> 6;
    const int p    = blockIdx.x * 4 + widx;   // point id in [0, 2*NN)
    const int b    = p >> 14;                  // batch (NN = 16384)

    float (*feat)[68] = s_feat[widx];
    float (*xyzd)[4]  = s_xyz[widx];

    const bf16x8* L0h = (const bf16x8*)(wf + WS_L0H);
    const bf16x8* L0l = (const bf16x8*)(wf + WS_L0L);
    const bf16x8* L1h = (const bf16x8*)(wf + WS_L1H);
    const bf16x8* L1l = (const bf16x8*)(wf + WS_L1L);
    const bf16x8* L2h = (const bf16x8*)(wf + WS_L2H);
    const bf16x8* L2l = (const bf16x8*)(wf + WS_L2L);
    const float*  bias = (const float*)(wf + WS_BIAS);

    // ---- gather: 32 neighbor rows x 64 feats + xyz_diff ----
    {
        const int r  = t & 31;
        const int hh = t >> 5;
        const int   idx = nidx[(size_t)p * 32 + r];
        const float m   = vmask[(size_t)p * 32 + r];
        const float* src = points_proj + ((size_t)b * HW + idx) * 64 + hh * 32;
        #pragma unroll
        for (int q = 0; q < 8; ++q) {
            float4 v = ((const float4*)src)[q];
            v.x *= m; v.y *= m; v.z *= m; v.w *= m;
            *((float4*)&feat[r][hh * 32 + 4 * q]) = v;
        }
        if (hh == 0) {
            const float* xs = xyz_proj + ((size_t)b * HW + idx) * 3;
            float nx = xyz_sampled[(size_t)p * 3 + 0];
            float ny = xyz_sampled[(size_t)p * 3 + 1];
            float nz = xyz_sampled[(size_t)p * 3 + 2];
            xyzd[r][0] = xs[0] * m - nx;
            xyzd[r][1] = xs[1] * m - ny;
            xyzd[r][2] = xs[2] * m - nz;
            xyzd[r][3] = 0.f;
        }
    }
    __syncthreads();

    // ---- layer 0: K = 64 (pts) + 3 (xyz) -> 64 ----
    f32x4 acc0[2][4] = {};
    #pragma unroll
    for (int kt = 0; kt < 2; ++kt) {
        bf16x8 ah[2], al[2];
        #pragma unroll
        for (int mt = 0; mt < 2; ++mt) {
            const float* fp = &feat[mt * 16 + (t & 15)][kt * 32 + 8 * (t >> 4)];
            float f[8];
            *(float4*)&f[0] = *(const float4*)fp;
            *(float4*)&f[4] = *(const float4*)(fp + 4);
            split_frag8(f, &ah[mt], &al[mt]);
        }
        #pragma unroll
        for (int nt = 0; nt < 4; ++nt) {
            bf16x8 wh = L0h[(kt * 4 + nt) * 64 + t];
            bf16x8 wl = L0l[(kt * 4 + nt) * 64 + t];
            #pragma unroll
            for (int mt = 0; mt < 2; ++mt)
                acc0[mt][nt] = mfma3(ah[mt], al[mt], wh, wl, acc0[mt][nt]);
        }
    }
    {   // xyz k-step (kt = 2): only lanes with (t>>4)==0, e<3 carry data
        bf16x8 ah[2], al[2];
        #pragma unroll
        for (int mt = 0; mt < 2; ++mt) {
            float f[8];
            #pragma unroll
            for (int e = 0; e < 8; ++e) f[e] = 0.f;
            if ((t >> 4) == 0) {
                int row = mt * 16 + (t & 15);
                f[0] = xyzd[row][0];
                f[1] = xyzd[row][1];
                f[2] = xyzd[row][2];
            }
            split_frag8(f, &ah[mt], &al[mt]);
        }
        #pragma unroll
        for (int nt = 0; nt < 4; ++nt) {
            bf16x8 wh = L0h[(2 * 4 + nt) * 64 + t];
            bf16x8 wl = L0l[(2 * 4 + nt) * 64 + t];
            #pragma unroll
            for (int mt = 0; mt < 2; ++mt)
                acc0[mt][nt] = mfma3(ah[mt], al[mt], wh, wl, acc0[mt][nt]);
        }
    }
    {   // bias + relu -> write act0 into feat[*][0..63]
        float bb[4];
        #pragma unroll
        for (int nt = 0; nt < 4; ++nt) bb[nt] = bias[nt * 16 + (t & 15)];
        #pragma unroll
        for (int mt = 0; mt < 2; ++mt)
            #pragma unroll
            for (int nt = 0; nt < 4; ++nt)
                #pragma unroll
                for (int r = 0; r < 4; ++r) {
                    float y = acc0[mt][nt][r] + bb[nt];
                    feat[mt * 16 + (t >> 4) * 4 + r][nt * 16 + (t & 15)] =
                        y > 0.f ? y : 0.f;
                }
    }
    __syncthreads();

    // ---- layer 1: 64 -> 64 ----
    f32x4 acc1[2][4] = {};
    #pragma unroll
    for (int kt = 0; kt < 2; ++kt) {
        bf16x8 ah[2], al[2];
        #pragma unroll
        for (int mt = 0; mt < 2; ++mt) {
            const float* fp = &feat[mt * 16 + (t & 15)][kt * 32 + 8 * (t >> 4)];
            float f[8];
            *(float4*)&f[0] = *(const float4*)fp;
            *(float4*)&f[4] = *(const float4*)(fp + 4);
            split_frag8(f, &ah[mt], &al[mt]);
        }
        #pragma unroll
        for (int nt = 0; nt < 4; ++nt) {
            bf16x8 wh = L1h[(kt * 4 + nt) * 64 + t];
            bf16x8 wl = L1l[(kt * 4 + nt) * 64 + t];
            #pragma unroll
            for (int mt = 0; mt < 2; ++mt)
                acc1[mt][nt] = mfma3(ah[mt], al[mt], wh, wl, acc1[mt][nt]);
        }
    }
    {
        float bb[4];
        #pragma unroll
        for (int nt = 0; nt < 4; ++nt) bb[nt] = bias[64 + nt * 16 + (t & 15)];
        #pragma unroll
        for (int mt = 0; mt < 2; ++mt)
            #pragma unroll
            for (int nt = 0; nt < 4; ++nt)
                #pragma unroll
                for (int r = 0; r < 4; ++r) {
                    float y = acc1[mt][nt][r] + bb[nt];
                    feat[mt * 16 + (t >> 4) * 4 + r][nt * 16 + (t & 15)] =
                        y > 0.f ? y : 0.f;
                }
    }
    __syncthreads();

    // ---- layer 2: 64 -> 128, fused maxpool + store ----
    bf16x8 a2h[2][2], a2l[2][2];   // [kt][mt]
    #pragma unroll
    for (int kt = 0; kt < 2; ++kt)
        #pragma unroll
        for (int mt = 0; mt < 2; ++mt) {
            const float* fp = &feat[mt * 16 + (t & 15)][kt * 32 + 8 * (t >> 4)];
            float f[8];
            *(float4*)&f[0] = *(const float4*)fp;
            *(float4*)&f[4] = *(const float4*)(fp + 4);
            split_frag8(f, &a2h[kt][mt], &a2l[kt][mt]);
        }

    #pragma unroll
    for (int nh = 0; nh < 2; ++nh) {
        f32x4 acc[2][4] = {};
        #pragma unroll
        for (int kt = 0; kt < 2; ++kt)
            #pragma unroll
            for (int nt = 0; nt < 4; ++nt) {
                bf16x8 wh = L2h[(kt * 8 + nh * 4 + nt) * 64 + t];
                bf16x8 wl = L2l[(kt * 8 + nh * 4 + nt) * 64 + t];
                #pragma unroll
                for (int mt = 0; mt < 2; ++mt)
                    acc[mt][nt] = mfma3(a2h[kt][mt], a2l[kt][mt], wh, wl, acc[mt][nt]);
            }
        float vnt[4];
        #pragma unroll
        for (int nt = 0; nt < 4; ++nt) {
            float bb = bias[128 + nh * 64 + nt * 16 + (t & 15)];
            float mx = acc[0][nt][0];
            #pragma unroll
            for (int r = 1; r < 4; ++r) mx = fmaxf(mx, acc[0][nt][r]);
            #pragma unroll
            for (int r = 0; r < 4; ++r) mx = fmaxf(mx, acc[1][nt][r]);
            float v = mx + bb;
            v = v > 0.f ? v : 0.f;            // relu commutes with max (bb const)
            v = fmaxf(v, __shfl_xor(v, 16));
            v = fmaxf(v, __shfl_xor(v, 32));
            vnt[nt] = v;
        }
        // lane t outputs column (nh*64 + t): pick vnt[t>>4]
        const int g = t >> 4;
        float v01 = (g & 1) ? vnt[1] : vnt[0];
        float v23 = (g & 1) ? vnt[3] : vnt[2];
        float val = (g & 2) ? v23 : v01;
        size_t o = (size_t)p * 128 + nh * 64 + t;
        out[o] = val;
        out[o + OUT_HALF] = val;
    }
}

extern "C" void kernel_launch(void* const* d_in, const int* in_sizes, int n_in,
                              void* d_out, int out_size, void* d_ws, size_t ws_size,
                              hipStream_t stream) {
    const float* xyz_proj    = (const float*)d_in[0];
    const float* points_proj = (const float*)d_in[1];
    const float* xyz_sampled = (const float*)d_in[2];
    const int*   neighbor_idx= (const int*)  d_in[3];
    const float* valid_mask  = (const float*)d_in[4];
    const float* W0 = (const float*)d_in[5];
    const float* b0 = (const float*)d_in[6];
    const float* g0 = (const float*)d_in[7];
    const float* be0= (const float*)d_in[8];
    const float* W1 = (const float*)d_in[9];
    const float* b1 = (const float*)d_in[10];
    const float* g1 = (const float*)d_in[11];
    const float* be1= (const float*)d_in[12];
    const float* W2 = (const float*)d_in[13];
    const float* b2 = (const float*)d_in[14];
    const float* g2 = (const float*)d_in[15];
    const float* be2= (const float*)d_in[16];

    uint16_t* ws = (uint16_t*)d_ws;

    prep_weights<<<64, 256, 0, stream>>>(W0, b0, g0, be0,
                                         W1, b1, g1, be1,
                                         W2, b2, g2, be2, ws);

    // 32768 points, 4 point-waves per block
    pointnet_mfma<<<8192, 256, 0, stream>>>(
        xyz_proj, points_proj, xyz_sampled, neighbor_idx, valid_mask,
        ws, (float*)d_out);
}